// Round 10
// baseline (166.624 us; speedup 1.0000x reference)
//
#include <hip/hip_runtime.h>
#include <math.h>

#define NPTS   2048      // N
#define LFEAT  56        // C*L
#define HFEAT  128       // H
#define HALFW  8
#define NEIGH  17
#define FROWS  16        // rows per feat block

// ---------------------------------------------------------------------------
// Kernel A: conv(dot over L) + BN + LeakyReLU for BOTH sources.
// Weights: 14 float4 in VGPRs per thread (thread owns h).
// x rows: staged in LDS, read as wave-broadcast ds_read_b128 (same address
// across all lanes -> conflict-free). Two rows in flight to break dep chains.
// Row space: rows [0, R) = input, rows [R, 2R) = state_memory, R = B*N.
// ---------------------------------------------------------------------------
__global__ __launch_bounds__(128) void feat_kernel(
    const float* __restrict__ x_in, const float* __restrict__ x_mem,
    const float* __restrict__ conv_w, const float* __restrict__ conv_b,
    const float* __restrict__ gamma,  const float* __restrict__ beta,
    const float* __restrict__ bmean,  const float* __restrict__ bvar,
    float* __restrict__ f_all, int R)
{
    __shared__ float4 xs[FROWS * 14];       // 16 rows x 56 floats = 3584 B

    const int h    = threadIdx.x;           // 0..127
    const int base = blockIdx.x * FROWS;    // uniform

    const float* src;
    int srow;
    if (base < R) { src = x_in;  srow = base; }
    else          { src = x_mem; srow = base - R; }

    // stage x tile (rows are contiguous: FROWS*56 floats = FROWS*14 float4)
    const float4* src4 = (const float4*)(src + (long)srow * LFEAT);
    for (int i = h; i < FROWS * 14; i += 128) xs[i] = src4[i];

    // conv_w row -> 14 float4 = 56 VGPRs (statically indexed)
    float4 w4[14];
    #pragma unroll
    for (int q = 0; q < 14; ++q)
        w4[q] = ((const float4*)(conv_w + h * LFEAT))[q];

    // fold BN: f = dot*sc + sh
    const float sc = gamma[h] / sqrtf(bvar[h] + 1e-5f);
    const float sh = (conv_b[h] - bmean[h]) * sc + beta[h];

    __syncthreads();

    for (int r = 0; r < FROWS; r += 2) {
        float a = 0.0f, b = 0.0f;           // two independent chains
        #pragma unroll
        for (int q = 0; q < 14; ++q) {
            const float4 xa = xs[r * 14 + q];
            const float4 xb = xs[(r + 1) * 14 + q];
            a = fmaf(xa.x, w4[q].x, a); a = fmaf(xa.y, w4[q].y, a);
            a = fmaf(xa.z, w4[q].z, a); a = fmaf(xa.w, w4[q].w, a);
            b = fmaf(xb.x, w4[q].x, b); b = fmaf(xb.y, w4[q].y, b);
            b = fmaf(xb.z, w4[q].z, b); b = fmaf(xb.w, w4[q].w, b);
        }
        float fa = a * sc + sh;
        float fb = b * sc + sh;
        fa = (fa >= 0.0f) ? fa : 0.1f * fa;  // LeakyReLU(0.1)
        fb = (fb >= 0.0f) ? fb : 0.1f * fb;
        f_all[(long)(base + r    ) * HFEAT + h] = fa;   // coalesced over h
        f_all[(long)(base + r + 1) * HFEAT + h] = fb;
    }
}

// ---------------------------------------------------------------------------
// Kernel B: banded attention, lane-per-neighbor layout. One wave per row.
//   lanes 0..16 : lane w computes sim(n, n-8+w) (128-dot); others -> -1e30
//   softmax     : 5+5 shfl_xor butterfly within the 32-lane half
//   broadcast   : 17 compile-time __shfl (v_readlane -> SGPR operand)
//   PV + blend  : lanes 0..55, coalesced loads of raw state_memory
// OOB neighbors: clamped address (always in-bounds), weight exactly 0.
// ---------------------------------------------------------------------------
__global__ __launch_bounds__(256) void attn_kernel(
    const float* __restrict__ f_all,
    const float* __restrict__ x_in, const float* __restrict__ x_mem,
    float* __restrict__ out, int R)
{
    const int wave = threadIdx.x >> 6;
    const int lane = threadIdx.x & 63;
    const int row  = blockIdx.x * 4 + wave;
    if (row >= R) return;

    const int n     = row & (NPTS - 1);   // position within batch (N=2048 pow2)
    const int bbase = row - n;            // batch start row

    // ---- QK: lane w = lane index; clamp keeps every load in-bounds
    const int  mw     = n - HALFW + lane;
    const int  mclamp = min(max(mw, 0), NPTS - 1);
    const bool valid  = (lane < NEIGH) && (mw >= 0) && (mw < NPTS);

    const float4* fin = (const float4*)(f_all + (long)row * HFEAT);            // uniform addr
    const float4* fmr = (const float4*)(f_all + (long)(R + bbase + mclamp) * HFEAT);

    float4 a0 = {0.f, 0.f, 0.f, 0.f}, a1 = {0.f, 0.f, 0.f, 0.f};
    #pragma unroll 4
    for (int q = 0; q < 32; q += 2) {
        const float4 xi0 = fin[q],     xm0 = fmr[q];
        const float4 xi1 = fin[q + 1], xm1 = fmr[q + 1];
        a0.x = fmaf(xi0.x, xm0.x, a0.x); a0.y = fmaf(xi0.y, xm0.y, a0.y);
        a0.z = fmaf(xi0.z, xm0.z, a0.z); a0.w = fmaf(xi0.w, xm0.w, a0.w);
        a1.x = fmaf(xi1.x, xm1.x, a1.x); a1.y = fmaf(xi1.y, xm1.y, a1.y);
        a1.z = fmaf(xi1.z, xm1.z, a1.z); a1.w = fmaf(xi1.w, xm1.w, a1.w);
    }
    float p = ((a0.x + a0.y) + (a0.z + a0.w)) + ((a1.x + a1.y) + (a1.z + a1.w));
    p = valid ? p : -1e30f;

    // ---- softmax across the 32-lane half (lanes 17..31 carry -1e30 -> e=0)
    float mx = p;
    #pragma unroll
    for (int off = 16; off >= 1; off >>= 1)
        mx = fmaxf(mx, __shfl_xor(mx, off));
    const float e = expf(p - mx);
    float sum = e;
    #pragma unroll
    for (int off = 16; off >= 1; off >>= 1)
        sum += __shfl_xor(sum, off);
    const float pn = e / sum;             // lanes 0..16 hold normalized weights

    // ---- broadcast the 17 weights (compile-time lane -> v_readlane)
    float swv[NEIGH];
    #pragma unroll
    for (int w = 0; w < NEIGH; ++w) swv[w] = __shfl(pn, w);

    // ---- PV against raw state_memory + blend (RATE = 0.5)
    if (lane < LFEAT) {
        const float* memb = x_mem + (long)bbase * LFEAT;
        float acc = 0.0f;
        #pragma unroll
        for (int w = 0; w < NEIGH; ++w) {
            const int m = min(max(n - HALFW + w, 0), NPTS - 1);  // weight 0 if OOB
            acc = fmaf(swv[w], memb[(long)m * LFEAT + lane], acc);
        }
        const long o = (long)row * LFEAT + lane;
        out[o] = 0.5f * x_in[o] + 0.5f * acc;
    }
}

// ---------------------------------------------------------------------------
extern "C" void kernel_launch(void* const* d_in, const int* in_sizes, int n_in,
                              void* d_out, int out_size, void* d_ws, size_t ws_size,
                              hipStream_t stream)
{
    const float* input  = (const float*)d_in[0];
    const float* smem   = (const float*)d_in[1];
    const float* conv_w = (const float*)d_in[2];
    const float* conv_b = (const float*)d_in[3];
    const float* gamma  = (const float*)d_in[4];
    const float* beta   = (const float*)d_in[5];
    const float* bmean  = (const float*)d_in[6];
    const float* bvar   = (const float*)d_in[7];
    float* out = (float*)d_out;

    const int R = in_sizes[0] / LFEAT;   // B*N = 16384
    float* f_all = (float*)d_ws;         // 2*R*128 floats = 16 MB

    const int blocksA = (2 * R) / FROWS;   // 2048 blocks, 128 threads
    feat_kernel<<<blocksA, 128, 0, stream>>>(input, smem, conv_w, conv_b,
                                             gamma, beta, bmean, bvar, f_all, R);

    const int blocksB = R / 4;             // 4096 blocks, 4 waves, 1 row/wave
    attn_kernel<<<blocksB, 256, 0, stream>>>(f_all, input, smem, out, R);
}

// Round 11
// 117.988 us; speedup vs baseline: 1.4122x; 1.4122x over previous
//
#include <hip/hip_runtime.h>
#include <math.h>

#define NPTS   2048      // N
#define LFEAT  56        // C*L
#define HFEAT  128       // H
#define HALFW  8
#define NEIGH  17
#define FROWS  16        // rows per feat block
#define BR     32        // rows per attn block (chunk within one batch)
#define BAND   48        // BR + 2*HALFW
#define LDW    132       // 128 + 4 floats pad (16B-aligned rows, breaks bank stride)

// ---------------------------------------------------------------------------
// Kernel A (unchanged from round 10): conv + BN + LeakyReLU for BOTH sources.
// ---------------------------------------------------------------------------
__global__ __launch_bounds__(128) void feat_kernel(
    const float* __restrict__ x_in, const float* __restrict__ x_mem,
    const float* __restrict__ conv_w, const float* __restrict__ conv_b,
    const float* __restrict__ gamma,  const float* __restrict__ beta,
    const float* __restrict__ bmean,  const float* __restrict__ bvar,
    float* __restrict__ f_all, int R)
{
    __shared__ float4 xs[FROWS * 14];       // 16 rows x 56 floats = 3584 B

    const int h    = threadIdx.x;           // 0..127
    const int base = blockIdx.x * FROWS;    // uniform

    const float* src;
    int srow;
    if (base < R) { src = x_in;  srow = base; }
    else          { src = x_mem; srow = base - R; }

    const float4* src4 = (const float4*)(src + (long)srow * LFEAT);
    for (int i = h; i < FROWS * 14; i += 128) xs[i] = src4[i];

    float4 w4[14];
    #pragma unroll
    for (int q = 0; q < 14; ++q)
        w4[q] = ((const float4*)(conv_w + h * LFEAT))[q];

    const float sc = gamma[h] / sqrtf(bvar[h] + 1e-5f);
    const float sh = (conv_b[h] - bmean[h]) * sc + beta[h];

    __syncthreads();

    for (int r = 0; r < FROWS; r += 2) {
        float a = 0.0f, b = 0.0f;
        #pragma unroll
        for (int q = 0; q < 14; ++q) {
            const float4 xa = xs[r * 14 + q];
            const float4 xb = xs[(r + 1) * 14 + q];
            a = fmaf(xa.x, w4[q].x, a); a = fmaf(xa.y, w4[q].y, a);
            a = fmaf(xa.z, w4[q].z, a); a = fmaf(xa.w, w4[q].w, a);
            b = fmaf(xb.x, w4[q].x, b); b = fmaf(xb.y, w4[q].y, b);
            b = fmaf(xb.z, w4[q].z, b); b = fmaf(xb.w, w4[q].w, b);
        }
        float fa = a * sc + sh;
        float fb = b * sc + sh;
        fa = (fa >= 0.0f) ? fa : 0.1f * fa;
        fb = (fb >= 0.0f) ? fb : 0.1f * fb;
        f_all[(long)(base + r    ) * HFEAT + h] = fa;
        f_all[(long)(base + r + 1) * HFEAT + h] = fb;
    }
}

// ---------------------------------------------------------------------------
// Kernel B: banded attention with LDS-staged f_mem band.
// Block = 512 thr (8 waves) handles BR=32 rows of one batch.
//   stage: f_mem rows clamp(c0-8 .. c0+39) -> LDS, coalesced (each row once)
//   QK   : 2 rows/pass (rowA lanes 0-31, rowB lanes 32-63); lane w in each
//          half dots f_in[row] (broadcast global) with LDS band row; 5+5
//          shfl_xor softmax within each 32-half
//   PV   : lanes 0-55, weights via compile-time __shfl (v_readlane), clamped
//          addresses with weight exactly 0 for OOB -> reference clamp mask
// ---------------------------------------------------------------------------
__global__ __launch_bounds__(512) void attn_kernel(
    const float* __restrict__ f_all,
    const float* __restrict__ x_in, const float* __restrict__ x_mem,
    float* __restrict__ out, int R)
{
    __shared__ float fs[BAND][LDW];         // 48 x 132 floats = 25.3 KB

    const int tid  = threadIdx.x;
    const int wave = tid >> 6;              // 0..7
    const int lane = tid & 63;

    const int chunks = NPTS / BR;           // 64
    const int b      = blockIdx.x / chunks;
    const int c0     = (blockIdx.x - b * chunks) * BR;
    const int bbase  = b * NPTS;

    // ---- stage f_mem band (coalesced; 32 float4 per row)
    for (int i = tid; i < BAND * 32; i += 512) {
        const int r = i >> 5;
        const int q = i & 31;
        const int g = min(max(c0 - HALFW + r, 0), NPTS - 1);
        const float4 v = ((const float4*)(f_all + (long)(R + bbase + g) * HFEAT))[q];
        *((float4*)&fs[r][4 * q]) = v;
    }
    __syncthreads();

    const int lh = lane & 31;               // lane within 32-half

    // each wave: 4 rows, 2 per pass
    #pragma unroll
    for (int rr = 0; rr < 4; rr += 2) {
        const int nA  = c0 + wave * 4 + rr;          // half 0's row (in batch)
        const int n   = nA + (lane >> 5);            // this half's row
        const int row = bbase + n;

        // ---- QK on lanes lh < 17 of each half
        const int  mw    = n - HALFW + lh;
        const int  mc    = min(max(mw, 0), NPTS - 1);
        const int  slot  = mc - c0 + HALFW;          // LDS band slot
        const bool valid = (lh < NEIGH) && (mw >= 0) && (mw < NPTS);

        float p = -1e30f;
        if (lh < NEIGH) {
            const float4* fin = (const float4*)(f_all + (long)row * HFEAT); // half-uniform
            const float4* fm  = (const float4*)&fs[slot][0];
            float4 a0 = {0.f,0.f,0.f,0.f}, a1 = {0.f,0.f,0.f,0.f};
            #pragma unroll
            for (int q = 0; q < 32; q += 2) {
                const float4 xi0 = fin[q],     xm0 = fm[q];
                const float4 xi1 = fin[q + 1], xm1 = fm[q + 1];
                a0.x = fmaf(xi0.x, xm0.x, a0.x); a0.y = fmaf(xi0.y, xm0.y, a0.y);
                a0.z = fmaf(xi0.z, xm0.z, a0.z); a0.w = fmaf(xi0.w, xm0.w, a0.w);
                a1.x = fmaf(xi1.x, xm1.x, a1.x); a1.y = fmaf(xi1.y, xm1.y, a1.y);
                a1.z = fmaf(xi1.z, xm1.z, a1.z); a1.w = fmaf(xi1.w, xm1.w, a1.w);
            }
            p = ((a0.x + a0.y) + (a0.z + a0.w)) + ((a1.x + a1.y) + (a1.z + a1.w));
            p = valid ? p : -1e30f;
        }

        // ---- softmax within each 32-half (invalid lanes: exp -> 0)
        float mx = p;
        #pragma unroll
        for (int off = 16; off >= 1; off >>= 1)
            mx = fmaxf(mx, __shfl_xor(mx, off));
        const float e = expf(p - mx);
        float sum = e;
        #pragma unroll
        for (int off = 16; off >= 1; off >>= 1)
            sum += __shfl_xor(sum, off);
        const float pn = e / sum;

        // ---- broadcast weights for both rows (compile-time lane -> readlane)
        float swA[NEIGH], swB[NEIGH];
        #pragma unroll
        for (int w = 0; w < NEIGH; ++w) {
            swA[w] = __shfl(pn, w);
            swB[w] = __shfl(pn, 32 + w);
        }

        // ---- PV + blend, lanes 0..55, both rows
        if (lane < LFEAT) {
            const float* memb = x_mem + (long)bbase * LFEAT;

            float accA = 0.0f, accB = 0.0f;
            #pragma unroll
            for (int w = 0; w < NEIGH; ++w) {
                const int mA = min(max(nA     - HALFW + w, 0), NPTS - 1);
                const int mB = min(max(nA + 1 - HALFW + w, 0), NPTS - 1);
                accA = fmaf(swA[w], memb[(long)mA * LFEAT + lane], accA);
                accB = fmaf(swB[w], memb[(long)mB * LFEAT + lane], accB);
            }
            const long oA = (long)(bbase + nA) * LFEAT + lane;
            const long oB = oA + LFEAT;
            out[oA] = 0.5f * x_in[oA] + 0.5f * accA;
            out[oB] = 0.5f * x_in[oB] + 0.5f * accB;
        }
    }
}

// ---------------------------------------------------------------------------
extern "C" void kernel_launch(void* const* d_in, const int* in_sizes, int n_in,
                              void* d_out, int out_size, void* d_ws, size_t ws_size,
                              hipStream_t stream)
{
    const float* input  = (const float*)d_in[0];
    const float* smem   = (const float*)d_in[1];
    const float* conv_w = (const float*)d_in[2];
    const float* conv_b = (const float*)d_in[3];
    const float* gamma  = (const float*)d_in[4];
    const float* beta   = (const float*)d_in[5];
    const float* bmean  = (const float*)d_in[6];
    const float* bvar   = (const float*)d_in[7];
    float* out = (float*)d_out;

    const int R = in_sizes[0] / LFEAT;   // B*N = 16384
    float* f_all = (float*)d_ws;         // 2*R*128 floats = 16 MB

    const int blocksA = (2 * R) / FROWS;   // 2048 blocks, 128 threads
    feat_kernel<<<blocksA, 128, 0, stream>>>(input, smem, conv_w, conv_b,
                                             gamma, beta, bmean, bvar, f_all, R);

    const int blocksB = (R / NPTS) * (NPTS / BR);   // B * 64 = 512 blocks
    attn_kernel<<<blocksB, 512, 0, stream>>>(f_all, input, smem, out, R);
}